// Round 12
// baseline (68.056 us; speedup 1.0000x reference)
//
#include <hip/hip_runtime.h>

// Problem: N=65536 rows, H=512, E=8, OUT=2.
//   oh=x[:,0:8], delta=x[:,8], phi=x[:,9]
//   h  = relu(delta*w1 + b1 + phi*(oh@meta_w) + oh@meta_b)   -> one K=32 bf16 MFMA GEMM
//   h2 = relu(h @ w2 + b2)                                   -> main GEMM, 32x32x16 bf16 MFMA
//   out = h2 @ w3 + b3                                       -> fused shuffle-reduce epilogue
//
// R12: R11's iteration shape (32 K per iter, 4KB bf per iter, long MFMA runs)
// but built from 32x32x16 frags (half the operand VGPRs of 16x16x32) so a
// 1-deep bf prefetch FITS the 64-VGPR VALU budget:
//   acc[2][2] f32x16 = 64 AGPR ; af 16 + bfA 16 + bfB 16 + addr ~8 = ~56 VGPR
//   -> 120 unified < 128 cap at __launch_bounds__(512,4): 2 blocks/CU, clean.
// Ping-pong bfA/bfB (no per-iter reg copies), peeled last double-iter (no
// prefetch overrun). 8 MFMA x 8cy = 64cy runs per 4KB loaded (R10's failure
// was 32cy runs; R11 proved the budget, R10 proved the 32x32 layout).

#define BM 64

typedef float f32x4  __attribute__((ext_vector_type(4)));
typedef float f32x16 __attribute__((ext_vector_type(16)));
typedef short s16x8  __attribute__((ext_vector_type(8)));

__device__ __forceinline__ short f2bf(float f) {
    union { float f; unsigned u; } c; c.f = f;
    unsigned u = c.u;
    return (short)((u + 0x7FFFu + ((u >> 16) & 1u)) >> 16);  // RNE
}

// ---------------- prep: build bf16 weight images in workspace ----------------
// w2s layout: [kg=k>>3][n=512][j=k&7] bf16 (fragment order; valid for both
//   16x16x32 and 32x32x16 paths)
// waugS layout: [col=512][k=32] bf16, rows of W' = [meta_w(8); meta_b(8); w1; b1; 0...]
__global__ void prep_kernel(const float* __restrict__ w1, const float* __restrict__ b1,
                            const float* __restrict__ mw, const float* __restrict__ mb,
                            const float* __restrict__ w2,
                            short* __restrict__ w2s, short* __restrict__ waugS) {
    int id = blockIdx.x * 256 + threadIdx.x;
    if (id < 512 * 512) {
        int k = id / 512, n = id % 512;
        w2s[((k >> 3) * 512 + n) * 8 + (k & 7)] = f2bf(w2[id]);
    }
    if (id < 512 * 32) {
        int col = id >> 5, k = id & 31;
        float v = 0.f;
        if (k < 8)        v = mw[k * 512 + col];
        else if (k < 16)  v = mb[(k - 8) * 512 + col];
        else if (k == 16) v = w1[col];
        else if (k == 17) v = b1[col];
        waugS[col * 32 + k] = f2bf(v);
    }
}

// ---------------- fused MLP ----------------
// grid 1024 blocks x 512 threads (8 waves). Block tile: 64 rows x 512 cols.
// Wave w owns cols [w*64, w*64+64), all 64 rows -> acc 2(mb) x 2(cb) 32x32 frags.
__global__ __launch_bounds__(512, 4) void fused_mlp(
    const float* __restrict__ x, const short* __restrict__ waugS,
    const short* __restrict__ w2s, const float* __restrict__ b2,
    const float* __restrict__ w3, const float* __restrict__ b3,
    float* __restrict__ out) {

    // h in FRAGMENT order: short idx = (c>>3)*512 + row*8 + (c&7)
    __shared__ __align__(16) short haug[64 * 512];          // 64KB
    __shared__ float xls[64 * 10];                          // 2560 B
    __shared__ float oacc[128];                             // 512 B

    const int tid  = threadIdx.x;
    const int wv   = tid >> 6;           // 0..7
    const int lane = tid & 63;
    const int l15  = lane & 15;
    const int g    = lane >> 4;
    const int hi   = lane >> 5;          // 0..1
    const int l31  = lane & 31;
    const long rowbase = (long)blockIdx.x * BM;

    // ---- load x tile (64x10 f32 = 640 floats, strided over 512 thr), zero out-acc ----
    for (int i = tid; i < BM * 10; i += 512) xls[i] = x[rowbase * 10 + i];
    if (tid < 128) oacc[tid] = 0.f;
    __syncthreads();

    // ---- layer 1: one K=32 MFMA pass (16x16x32); h -> LDS in fragment order ----
    {
        s16x8 afr[4];
#pragma unroll
        for (int m = 0; m < 4; ++m) {
            int r = m * 16 + l15;
            float v[8];
            if (g == 0) {                    // k=0..7 : oh * phi
                float phi = xls[r * 10 + 9];
#pragma unroll
                for (int j = 0; j < 8; ++j) v[j] = xls[r * 10 + j] * phi;
            } else if (g == 1) {             // k=8..15 : oh
#pragma unroll
                for (int j = 0; j < 8; ++j) v[j] = xls[r * 10 + j];
            } else if (g == 2) {             // k=16,17 : delta, 1
                v[0] = xls[r * 10 + 8]; v[1] = 1.f;
#pragma unroll
                for (int j = 2; j < 8; ++j) v[j] = 0.f;
            } else {                         // k=24..31 : 0
#pragma unroll
                for (int j = 0; j < 8; ++j) v[j] = 0.f;
            }
            s16x8 a;
#pragma unroll
            for (int j = 0; j < 8; ++j) a[j] = f2bf(v[j]);
            afr[m] = a;
        }
#pragma unroll
        for (int nf = 0; nf < 4; ++nf) {
            int col = wv * 64 + nf * 16 + l15;
            s16x8 bfr = *(const s16x8*)(waugS + col * 32 + g * 8);
            int chi = (col >> 3) * 512 + (col & 7);          // fragment-order column part
#pragma unroll
            for (int m = 0; m < 4; ++m) {
                f32x4 c = {0.f, 0.f, 0.f, 0.f};
                c = __builtin_amdgcn_mfma_f32_16x16x32_bf16(afr[m], bfr, c, 0, 0, 0);
#pragma unroll
                for (int r4 = 0; r4 < 4; ++r4) {
                    int row = m * 16 + g * 4 + r4;
                    float hv = c[r4];
                    hv = hv > 0.f ? hv : 0.f;
                    haug[chi + row * 8] = f2bf(hv);
                }
            }
        }
    }
    __syncthreads();   // h ready; haug read-only from here -> no more barriers

    // ---- layer 2: K=512 as 16 iters of K=32 (2 sub-steps of 32x32x16),
    //      ping-pong 1-deep bf prefetch, barrier-free ----
    f32x16 acc[2][2];
#pragma unroll
    for (int a = 0; a < 2; ++a)
#pragma unroll
        for (int b = 0; b < 2; ++b)
#pragma unroll
            for (int e = 0; e < 16; ++e) acc[a][b][e] = 0.f;

    // af: byte = (4t+2s+hi)*1024 + (mb*32+l31)*16  -> base + t*4096 + s*2048 + mb*512
    const char* hbp = (const char*)haug + hi * 1024 + l31 * 16;
    // bf: byte = (4t+2s+hi)*8192 + (wv*64+cb*32+l31)*16 -> base + t*32768 + s*16384 + cb*512
    const char* bfp = (const char*)w2s + hi * 8192 + (wv * 64 + l31) * 16;

#define LOADB(dst, base, T)                                            \
    do {                                                               \
        dst[0] = *(const s16x8*)((base) + (size_t)(T) * 32768);        \
        dst[1] = *(const s16x8*)((base) + (size_t)(T) * 32768 + 512);  \
        dst[2] = *(const s16x8*)((base) + (size_t)(T) * 32768 + 16384);\
        dst[3] = *(const s16x8*)((base) + (size_t)(T) * 32768 + 16896);\
    } while (0)

#define DOSTEP(bfv)                                                                          \
    do {                                                                                     \
        s16x8 a00 = *(const s16x8*)(hbp);                                                    \
        s16x8 a01 = *(const s16x8*)(hbp + 512);                                              \
        s16x8 a10 = *(const s16x8*)(hbp + 2048);                                             \
        s16x8 a11 = *(const s16x8*)(hbp + 2560);                                             \
        acc[0][0] = __builtin_amdgcn_mfma_f32_32x32x16_bf16(a00, bfv[0], acc[0][0], 0, 0, 0);\
        acc[0][1] = __builtin_amdgcn_mfma_f32_32x32x16_bf16(a00, bfv[1], acc[0][1], 0, 0, 0);\
        acc[1][0] = __builtin_amdgcn_mfma_f32_32x32x16_bf16(a01, bfv[0], acc[1][0], 0, 0, 0);\
        acc[1][1] = __builtin_amdgcn_mfma_f32_32x32x16_bf16(a01, bfv[1], acc[1][1], 0, 0, 0);\
        acc[0][0] = __builtin_amdgcn_mfma_f32_32x32x16_bf16(a10, bfv[2], acc[0][0], 0, 0, 0);\
        acc[0][1] = __builtin_amdgcn_mfma_f32_32x32x16_bf16(a10, bfv[3], acc[0][1], 0, 0, 0);\
        acc[1][0] = __builtin_amdgcn_mfma_f32_32x32x16_bf16(a11, bfv[2], acc[1][0], 0, 0, 0);\
        acc[1][1] = __builtin_amdgcn_mfma_f32_32x32x16_bf16(a11, bfv[3], acc[1][1], 0, 0, 0);\
        hbp += 4096;                                                                         \
    } while (0)

    s16x8 bfA[4], bfB[4];
    LOADB(bfA, bfp, 0);                       // t=0

#pragma unroll 1
    for (int tt = 0; tt < 7; ++tt) {
        LOADB(bfB, bfp, 2 * tt + 1);          // prefetch odd t
        DOSTEP(bfA);                          // consume even t = 2tt
        LOADB(bfA, bfp, 2 * tt + 2);          // prefetch next even t
        DOSTEP(bfB);                          // consume odd t = 2tt+1
    }
    LOADB(bfB, bfp, 15);                      // prefetch t=15 (last, in-bounds)
    DOSTEP(bfA);                              // t=14
    DOSTEP(bfB);                              // t=15

#undef LOADB
#undef DOSTEP

    // ---- layer 3: relu(acc+b2) @ w3, per-(mb,reg) immediate reduce ----
    // C/D 32x32 layout: col = l31, row = (reg&3) + 8*(reg>>2) + 4*hi   [m74/m101]
    float b2c[2], w30c[2], w31c[2];
#pragma unroll
    for (int cb = 0; cb < 2; ++cb) {
        int c = wv * 64 + cb * 32 + l31;
        b2c[cb] = b2[c];
        w30c[cb] = w3[c * 2 + 0];
        w31c[cb] = w3[c * 2 + 1];
    }
#pragma unroll
    for (int mb = 0; mb < 2; ++mb) {
#pragma unroll
        for (int reg = 0; reg < 16; ++reg) {
            float s0 = 0.f, s1 = 0.f;
#pragma unroll
            for (int cb = 0; cb < 2; ++cb) {
                float v = acc[mb][cb][reg] + b2c[cb];
                v = v > 0.f ? v : 0.f;
                s0 += v * w30c[cb];
                s1 += v * w31c[cb];
            }
            s0 += __shfl_xor(s0, 1);  s1 += __shfl_xor(s1, 1);
            s0 += __shfl_xor(s0, 2);  s1 += __shfl_xor(s1, 2);
            s0 += __shfl_xor(s0, 4);  s1 += __shfl_xor(s1, 4);
            s0 += __shfl_xor(s0, 8);  s1 += __shfl_xor(s1, 8);
            s0 += __shfl_xor(s0, 16); s1 += __shfl_xor(s1, 16);
            if (l31 == 0) {
                int row = mb * 32 + (reg & 3) + 8 * (reg >> 2) + 4 * hi;
                atomicAdd(&oacc[row * 2 + 0], s0);
                atomicAdd(&oacc[row * 2 + 1], s1);
            }
        }
    }
    __syncthreads();

    if (tid < 128) {
        int row = tid >> 1, o = tid & 1;
        out[(rowbase + row) * 2 + o] = oacc[tid] + b3[o];
    }
}

extern "C" void kernel_launch(void* const* d_in, const int* in_sizes, int n_in,
                              void* d_out, int out_size, void* d_ws, size_t ws_size,
                              hipStream_t stream) {
    const float* x  = (const float*)d_in[0];
    const float* w1 = (const float*)d_in[1];
    const float* b1 = (const float*)d_in[2];
    const float* mw = (const float*)d_in[3];
    const float* mb = (const float*)d_in[4];
    const float* w2 = (const float*)d_in[5];
    const float* b2 = (const float*)d_in[6];
    const float* w3 = (const float*)d_in[7];
    const float* b3 = (const float*)d_in[8];
    float* out = (float*)d_out;

    short* w2s   = (short*)d_ws;          // 512 KB
    short* waugS = w2s + 512 * 512;       // 32 KB

    prep_kernel<<<1024, 256, 0, stream>>>(w1, b1, mw, mb, w2, w2s, waugS);
    fused_mlp<<<65536 / BM, 512, 0, stream>>>(x, waugS, w2s, b2, w3, b3, out);
}